// Round 1
// baseline (913.502 us; speedup 1.0000x reference)
//
#include <hip/hip_runtime.h>

// GCN 2-layer: out = D_in^-1/2 A D_out^-1/2 (relu(D_in^-1/2 A D_out^-1/2 X W1 + b1)) W2 + b2
// Strategy: project-then-aggregate (matmul commutes with segment_sum),
// CSR-by-dst built per call (no fp32 atomics in aggregation).

static inline size_t align256(size_t x) { return (x + 255) & ~(size_t)255; }

__global__ void count_deg_kernel(const int* __restrict__ src,
                                 const int* __restrict__ dst,
                                 int* __restrict__ cnt_out,
                                 int* __restrict__ cnt_in, int E) {
    int stride = gridDim.x * blockDim.x;
    for (int i = blockIdx.x * blockDim.x + threadIdx.x; i < E; i += stride) {
        atomicAdd(&cnt_out[src[i]], 1);
        atomicAdd(&cnt_in[dst[i]], 1);
    }
}

// Single-block chunked exclusive scan of cnt_in -> row_ptr[0..N], cursor = row_ptr copy.
__global__ __launch_bounds__(1024)
void scan_rowptr_kernel(const int* __restrict__ cnt_in,
                        int* __restrict__ row_ptr,
                        int* __restrict__ cursor, int N) {
    __shared__ int sums[1024];
    const int t = threadIdx.x;
    const int chunk = (N + 1023) / 1024;
    const int lo = t * chunk;
    const int hi = min(lo + chunk, N);
    int s = 0;
    for (int i = lo; i < hi; ++i) s += cnt_in[i];
    sums[t] = s;
    __syncthreads();
    // Hillis-Steele inclusive scan over 1024 partials
    for (int off = 1; off < 1024; off <<= 1) {
        int v = (t >= off) ? sums[t - off] : 0;
        __syncthreads();
        sums[t] += v;
        __syncthreads();
    }
    int run = (t == 0) ? 0 : sums[t - 1];
    for (int i = lo; i < hi; ++i) {
        row_ptr[i] = run;
        cursor[i]  = run;
        run += cnt_in[i];
    }
    if (t == 0) row_ptr[N] = sums[1023];
}

__global__ void fill_csr_kernel(const int* __restrict__ src,
                                const int* __restrict__ dst,
                                int* __restrict__ cursor,
                                int* __restrict__ csr_src, int E) {
    int stride = gridDim.x * blockDim.x;
    for (int i = blockIdx.x * blockDim.x + threadIdx.x; i < E; i += stride) {
        int d = dst[i];
        int pos = atomicAdd(&cursor[d], 1);
        csr_src[pos] = src[i];
    }
}

// Y[n][j] = (sum_k X[n][k] * W[k][j]) * rsqrt(max(cnt_out[n],1))
// Block: 256 threads = 4 rows x 64 cols. W staged in LDS (K*64*4 B).
template <int K>
__global__ __launch_bounds__(256)
void gemm_scale_kernel(const float* __restrict__ X, const float* __restrict__ W,
                       const int* __restrict__ cnt_out,
                       float* __restrict__ Y, int N) {
    __shared__ float Ws[K][64];
    const int t = threadIdx.x;
    for (int i = t; i < K * 64; i += 256) Ws[i >> 6][i & 63] = W[i];
    __syncthreads();

    const int col = t & 63;
    const int row = blockIdx.x * 4 + (t >> 6);
    if (row >= N) return;

    const float* xr = X + (size_t)row * K;
    float acc = 0.f;
#pragma unroll
    for (int k = 0; k < K; k += 4) {
        float4 xv = *(const float4*)(xr + k);   // wave-uniform -> broadcast from L1
        acc += xv.x * Ws[k][col];
        acc += xv.y * Ws[k + 1][col];
        acc += xv.z * Ws[k + 2][col];
        acc += xv.w * Ws[k + 3][col];
    }
    float sc = rsqrtf((float)max(cnt_out[row], 1));
    Y[(size_t)row * 64 + col] = acc * sc;
}

// out[n][f] = (sum_{e in in-edges(n)} Y[src(e)][f]) * rsqrt(max(cnt_in[n],1)) + bias[f]
// One wave per node (lane = feature), 4 nodes / 256-thread block. No atomics.
template <bool RELU>
__global__ __launch_bounds__(256)
void aggregate_kernel(const float* __restrict__ Y,
                      const int* __restrict__ row_ptr,
                      const int* __restrict__ csr_src,
                      const int* __restrict__ cnt_in,
                      const float* __restrict__ bias,
                      float* __restrict__ out, int N) {
    const int f = threadIdx.x & 63;
    const int n = blockIdx.x * 4 + (threadIdx.x >> 6);
    if (n >= N) return;

    const int start = row_ptr[n];
    const int end   = row_ptr[n + 1];

    float acc = 0.f;
    int e = start;
    // 4-deep unroll for memory-level parallelism on the random row gathers
    for (; e + 4 <= end; e += 4) {
        int s0 = csr_src[e];
        int s1 = csr_src[e + 1];
        int s2 = csr_src[e + 2];
        int s3 = csr_src[e + 3];
        float v0 = Y[(size_t)s0 * 64 + f];
        float v1 = Y[(size_t)s1 * 64 + f];
        float v2 = Y[(size_t)s2 * 64 + f];
        float v3 = Y[(size_t)s3 * 64 + f];
        acc += v0 + v1 + v2 + v3;
    }
    for (; e < end; ++e) acc += Y[(size_t)csr_src[e] * 64 + f];

    float sc = rsqrtf((float)max(cnt_in[n], 1));
    float r = acc * sc + bias[f];
    if (RELU) r = fmaxf(r, 0.f);
    out[(size_t)n * 64 + f] = r;
}

extern "C" void kernel_launch(void* const* d_in, const int* in_sizes, int n_in,
                              void* d_out, int out_size, void* d_ws, size_t ws_size,
                              hipStream_t stream) {
    const float* x   = (const float*)d_in[0];
    const int*   src = (const int*)d_in[1];
    const int*   dst = (const int*)d_in[2];
    const float* W1  = (const float*)d_in[3];
    const float* b1  = (const float*)d_in[4];
    const float* W2  = (const float*)d_in[5];
    const float* b2  = (const float*)d_in[6];
    float* out = (float*)d_out;

    const int N = in_sizes[0] / 128;   // 100000
    const int E = in_sizes[1];         // 1600000

    // Workspace layout (~33 MB). d_out doubles as the hidden-layer buffer.
    char* ws = (char*)d_ws;
    size_t off = 0;
    float* A       = (float*)(ws + off); off = align256(off + (size_t)N * 64 * sizeof(float));
    int*   csr_src = (int*)(ws + off);   off = align256(off + (size_t)E * sizeof(int));
    int*   cnt_out = (int*)(ws + off);   off = align256(off + (size_t)N * sizeof(int));
    int*   cnt_in  = (int*)(ws + off);   off = align256(off + (size_t)N * sizeof(int));
    int*   row_ptr = (int*)(ws + off);   off = align256(off + (size_t)(N + 1) * sizeof(int));
    int*   cursor  = (int*)(ws + off);   off = align256(off + (size_t)N * sizeof(int));

    hipMemsetAsync(cnt_out, 0, (size_t)N * sizeof(int), stream);
    hipMemsetAsync(cnt_in,  0, (size_t)N * sizeof(int), stream);

    count_deg_kernel<<<2048, 256, 0, stream>>>(src, dst, cnt_out, cnt_in, E);
    scan_rowptr_kernel<<<1, 1024, 0, stream>>>(cnt_in, row_ptr, cursor, N);
    fill_csr_kernel<<<2048, 256, 0, stream>>>(src, dst, cursor, csr_src, E);

    const int nblocks = (N + 3) / 4;   // 4 rows/nodes per 256-thread block

    // Layer 1: Y1 = (X @ W1) * rs_out  -> ws A ; agg -> d_out (hidden, with relu)
    gemm_scale_kernel<128><<<nblocks, 256, 0, stream>>>(x, W1, cnt_out, A, N);
    aggregate_kernel<true><<<nblocks, 256, 0, stream>>>(A, row_ptr, csr_src, cnt_in, b1, out, N);

    // Layer 2: Y2 = (H @ W2) * rs_out -> ws A ; agg -> d_out (final, no relu)
    gemm_scale_kernel<64><<<nblocks, 256, 0, stream>>>(out, W2, cnt_out, A, N);
    aggregate_kernel<false><<<nblocks, 256, 0, stream>>>(A, row_ptr, csr_src, cnt_in, b2, out, N);
}

// Round 2
// 695.460 us; speedup vs baseline: 1.3135x; 1.3135x over previous
//
#include <hip/hip_runtime.h>

// GCN 2-layer: out = D_in^-1/2 A D_out^-1/2 (relu(D_in^-1/2 A D_out^-1/2 X W1 + b1)) W2 + b2
// Strategy: project-then-aggregate (matmul commutes with segment_sum),
// CSR-by-dst built per call (no fp32 atomics in aggregation).
// R1: replaced single-block scan (231 us, latency-bound) with 3-phase parallel scan.

static inline size_t align256(size_t x) { return (x + 255) & ~(size_t)255; }

__global__ void count_deg_kernel(const int* __restrict__ src,
                                 const int* __restrict__ dst,
                                 int* __restrict__ cnt_out,
                                 int* __restrict__ cnt_in, int E) {
    int stride = gridDim.x * blockDim.x;
    for (int i = blockIdx.x * blockDim.x + threadIdx.x; i < E; i += stride) {
        atomicAdd(&cnt_out[src[i]], 1);
        atomicAdd(&cnt_in[dst[i]], 1);
    }
}

// ---- 3-phase parallel exclusive scan of cnt_in -> row_ptr / cursor ----
// Phase 1: per-block local exclusive scan (512 elems/block), block totals out.
__global__ __launch_bounds__(512)
void scan_local_kernel(const int* __restrict__ cnt_in,
                       int* __restrict__ row_ptr,
                       int* __restrict__ block_sums, int N) {
    __shared__ int tmp[512];
    const int t = threadIdx.x;
    const int gid = blockIdx.x * 512 + t;
    int v = (gid < N) ? cnt_in[gid] : 0;
    tmp[t] = v;
    __syncthreads();
    for (int off = 1; off < 512; off <<= 1) {
        int u = (t >= off) ? tmp[t - off] : 0;
        __syncthreads();
        tmp[t] += u;
        __syncthreads();
    }
    if (gid < N) row_ptr[gid] = tmp[t] - v;      // exclusive
    if (t == 511) block_sums[blockIdx.x] = tmp[511];
}

// Phase 2: single-block exclusive scan of block sums (nb <= 1024).
__global__ __launch_bounds__(1024)
void scan_sums_kernel(int* __restrict__ block_sums, int nb) {
    __shared__ int tmp[1024];
    const int t = threadIdx.x;
    int v = (t < nb) ? block_sums[t] : 0;
    tmp[t] = v;
    __syncthreads();
    for (int off = 1; off < 1024; off <<= 1) {
        int u = (t >= off) ? tmp[t - off] : 0;
        __syncthreads();
        tmp[t] += u;
        __syncthreads();
    }
    if (t < nb) block_sums[t] = tmp[t] - v;      // exclusive
}

// Phase 3: add block offsets, emit cursor copy, row_ptr[N] = E.
__global__ __launch_bounds__(512)
void scan_add_kernel(int* __restrict__ row_ptr,
                     int* __restrict__ cursor,
                     const int* __restrict__ block_sums, int N, int E) {
    const int gid = blockIdx.x * 512 + threadIdx.x;
    if (gid < N) {
        int r = row_ptr[gid] + block_sums[blockIdx.x];
        row_ptr[gid] = r;
        cursor[gid]  = r;
    }
    if (gid == 0) row_ptr[N] = E;
}

__global__ void fill_csr_kernel(const int* __restrict__ src,
                                const int* __restrict__ dst,
                                int* __restrict__ cursor,
                                int* __restrict__ csr_src, int E) {
    int stride = gridDim.x * blockDim.x;
    for (int i = blockIdx.x * blockDim.x + threadIdx.x; i < E; i += stride) {
        int d = dst[i];
        int pos = atomicAdd(&cursor[d], 1);
        csr_src[pos] = src[i];
    }
}

// Y[n][j] = (sum_k X[n][k] * W[k][j]) * rsqrt(max(cnt_out[n],1))
// Block: 256 threads = 4 rows x 64 cols. W staged in LDS (K*64*4 B).
template <int K>
__global__ __launch_bounds__(256)
void gemm_scale_kernel(const float* __restrict__ X, const float* __restrict__ W,
                       const int* __restrict__ cnt_out,
                       float* __restrict__ Y, int N) {
    __shared__ float Ws[K][64];
    const int t = threadIdx.x;
    for (int i = t; i < K * 64; i += 256) Ws[i >> 6][i & 63] = W[i];
    __syncthreads();

    const int col = t & 63;
    const int row = blockIdx.x * 4 + (t >> 6);
    if (row >= N) return;

    const float* xr = X + (size_t)row * K;
    float acc = 0.f;
#pragma unroll
    for (int k = 0; k < K; k += 4) {
        float4 xv = *(const float4*)(xr + k);   // wave-uniform -> broadcast
        acc += xv.x * Ws[k][col];
        acc += xv.y * Ws[k + 1][col];
        acc += xv.z * Ws[k + 2][col];
        acc += xv.w * Ws[k + 3][col];
    }
    float sc = rsqrtf((float)max(cnt_out[row], 1));
    Y[(size_t)row * 64 + col] = acc * sc;
}

// out[n][f] = (sum_{in-edges} Y[src][f]) * rsqrt(max(cnt_in[n],1)) + bias[f]
// One wave per node (lane = feature), 4 nodes / 256-thread block. No atomics.
template <bool RELU>
__global__ __launch_bounds__(256)
void aggregate_kernel(const float* __restrict__ Y,
                      const int* __restrict__ row_ptr,
                      const int* __restrict__ csr_src,
                      const int* __restrict__ cnt_in,
                      const float* __restrict__ bias,
                      float* __restrict__ out, int N) {
    const int f = threadIdx.x & 63;
    const int n = blockIdx.x * 4 + (threadIdx.x >> 6);
    if (n >= N) return;

    const int start = row_ptr[n];
    const int end   = row_ptr[n + 1];

    float acc = 0.f;
    int e = start;
    for (; e + 4 <= end; e += 4) {
        int s0 = csr_src[e];
        int s1 = csr_src[e + 1];
        int s2 = csr_src[e + 2];
        int s3 = csr_src[e + 3];
        float v0 = Y[(size_t)s0 * 64 + f];
        float v1 = Y[(size_t)s1 * 64 + f];
        float v2 = Y[(size_t)s2 * 64 + f];
        float v3 = Y[(size_t)s3 * 64 + f];
        acc += v0 + v1 + v2 + v3;
    }
    for (; e < end; ++e) acc += Y[(size_t)csr_src[e] * 64 + f];

    float sc = rsqrtf((float)max(cnt_in[n], 1));
    float r = acc * sc + bias[f];
    if (RELU) r = fmaxf(r, 0.f);
    out[(size_t)n * 64 + f] = r;
}

extern "C" void kernel_launch(void* const* d_in, const int* in_sizes, int n_in,
                              void* d_out, int out_size, void* d_ws, size_t ws_size,
                              hipStream_t stream) {
    const float* x   = (const float*)d_in[0];
    const int*   src = (const int*)d_in[1];
    const int*   dst = (const int*)d_in[2];
    const float* W1  = (const float*)d_in[3];
    const float* b1  = (const float*)d_in[4];
    const float* W2  = (const float*)d_in[5];
    const float* b2  = (const float*)d_in[6];
    float* out = (float*)d_out;

    const int N = in_sizes[0] / 128;   // 100000
    const int E = in_sizes[1];         // 1600000

    const int SCAN_B = 512;
    const int nb = (N + SCAN_B - 1) / SCAN_B;   // 196 blocks

    // Workspace layout (~33 MB). d_out doubles as the hidden-layer buffer.
    char* ws = (char*)d_ws;
    size_t off = 0;
    float* A        = (float*)(ws + off); off = align256(off + (size_t)N * 64 * sizeof(float));
    int*   csr_src  = (int*)(ws + off);   off = align256(off + (size_t)E * sizeof(int));
    int*   cnt_out  = (int*)(ws + off);   off += (size_t)N * sizeof(int);      // contiguous with
    int*   cnt_in   = (int*)(ws + off);   off = align256(off + (size_t)N * sizeof(int)); // cnt_out
    int*   row_ptr  = (int*)(ws + off);   off = align256(off + (size_t)(N + 1) * sizeof(int));
    int*   cursor   = (int*)(ws + off);   off = align256(off + (size_t)N * sizeof(int));
    int*   blk_sums = (int*)(ws + off);   off = align256(off + (size_t)nb * sizeof(int));

    hipMemsetAsync(cnt_out, 0, (size_t)2 * N * sizeof(int), stream);  // cnt_out + cnt_in

    count_deg_kernel<<<2048, 256, 0, stream>>>(src, dst, cnt_out, cnt_in, E);
    scan_local_kernel<<<nb, SCAN_B, 0, stream>>>(cnt_in, row_ptr, blk_sums, N);
    scan_sums_kernel<<<1, 1024, 0, stream>>>(blk_sums, nb);
    scan_add_kernel<<<nb, SCAN_B, 0, stream>>>(row_ptr, cursor, blk_sums, N, E);
    fill_csr_kernel<<<2048, 256, 0, stream>>>(src, dst, cursor, csr_src, E);

    const int nblocks = (N + 3) / 4;   // 4 rows/nodes per 256-thread block

    // Layer 1: Y1 = (X @ W1) * rs_out -> A ; agg -> d_out (hidden, relu)
    gemm_scale_kernel<128><<<nblocks, 256, 0, stream>>>(x, W1, cnt_out, A, N);
    aggregate_kernel<true><<<nblocks, 256, 0, stream>>>(A, row_ptr, csr_src, cnt_in, b1, out, N);

    // Layer 2: Y2 = (H @ W2) * rs_out -> A ; agg -> d_out (final)
    gemm_scale_kernel<64><<<nblocks, 256, 0, stream>>>(out, W2, cnt_out, A, N);
    aggregate_kernel<false><<<nblocks, 256, 0, stream>>>(A, row_ptr, csr_src, cnt_in, b2, out, N);
}

// Round 3
// 555.045 us; speedup vs baseline: 1.6458x; 1.2530x over previous
//
#include <hip/hip_runtime.h>

// GCN 2-layer: out = D_in^-1/2 A D_out^-1/2 (relu(D_in^-1/2 A D_out^-1/2 X W1 + b1)) W2 + b2
// Strategy: project-then-aggregate (matmul commutes with segment_sum),
// CSR-by-dst built per call (no fp32 atomics in aggregation).
// R1: 3-phase parallel scan (scan was 231 us on one CU).
// R2: register-tiled GEMM — 4x4 outputs/thread, W staged once/block, X streamed
//     from global (was: 1 output/thread, 128 ds_read_b32 each, W restaged 25000x).

static inline size_t align256(size_t x) { return (x + 255) & ~(size_t)255; }

__global__ void count_deg_kernel(const int* __restrict__ src,
                                 const int* __restrict__ dst,
                                 int* __restrict__ cnt_out,
                                 int* __restrict__ cnt_in, int E) {
    int stride = gridDim.x * blockDim.x;
    for (int i = blockIdx.x * blockDim.x + threadIdx.x; i < E; i += stride) {
        atomicAdd(&cnt_out[src[i]], 1);
        atomicAdd(&cnt_in[dst[i]], 1);
    }
}

// ---- 3-phase parallel exclusive scan of cnt_in -> row_ptr / cursor ----
__global__ __launch_bounds__(512)
void scan_local_kernel(const int* __restrict__ cnt_in,
                       int* __restrict__ row_ptr,
                       int* __restrict__ block_sums, int N) {
    __shared__ int tmp[512];
    const int t = threadIdx.x;
    const int gid = blockIdx.x * 512 + t;
    int v = (gid < N) ? cnt_in[gid] : 0;
    tmp[t] = v;
    __syncthreads();
    for (int off = 1; off < 512; off <<= 1) {
        int u = (t >= off) ? tmp[t - off] : 0;
        __syncthreads();
        tmp[t] += u;
        __syncthreads();
    }
    if (gid < N) row_ptr[gid] = tmp[t] - v;      // exclusive
    if (t == 511) block_sums[blockIdx.x] = tmp[511];
}

__global__ __launch_bounds__(1024)
void scan_sums_kernel(int* __restrict__ block_sums, int nb) {
    __shared__ int tmp[1024];
    const int t = threadIdx.x;
    int v = (t < nb) ? block_sums[t] : 0;
    tmp[t] = v;
    __syncthreads();
    for (int off = 1; off < 1024; off <<= 1) {
        int u = (t >= off) ? tmp[t - off] : 0;
        __syncthreads();
        tmp[t] += u;
        __syncthreads();
    }
    if (t < nb) block_sums[t] = tmp[t] - v;      // exclusive
}

__global__ __launch_bounds__(512)
void scan_add_kernel(int* __restrict__ row_ptr,
                     int* __restrict__ cursor,
                     const int* __restrict__ block_sums, int N, int E) {
    const int gid = blockIdx.x * 512 + threadIdx.x;
    if (gid < N) {
        int r = row_ptr[gid] + block_sums[blockIdx.x];
        row_ptr[gid] = r;
        cursor[gid]  = r;
    }
    if (gid == 0) row_ptr[N] = E;
}

__global__ void fill_csr_kernel(const int* __restrict__ src,
                                const int* __restrict__ dst,
                                int* __restrict__ cursor,
                                int* __restrict__ csr_src, int E) {
    int stride = gridDim.x * blockDim.x;
    for (int i = blockIdx.x * blockDim.x + threadIdx.x; i < E; i += stride) {
        int d = dst[i];
        int pos = atomicAdd(&cursor[d], 1);
        csr_src[pos] = src[i];
    }
}

// Y[n][j] = (sum_k X[n][k] * W[k][j]) * rsqrt(max(cnt_out[n],1))
// Block: 256 threads = 64 rows x 64 cols; thread computes 4 rows x 4 cols.
// W in LDS (staged once); X streamed from global (wave-uniform row segments).
template <int K>
__global__ __launch_bounds__(256)
void gemm_scale_kernel(const float* __restrict__ X, const float* __restrict__ W,
                       const int* __restrict__ cnt_out,
                       float* __restrict__ Y, int N) {
    __shared__ float Ws[K][64];
    const int t = threadIdx.x;
    for (int i = t; i < K * 64; i += 256) Ws[i >> 6][i & 63] = W[i];
    __syncthreads();

    const int cid = t & 15;            // cols 4*cid .. 4*cid+3
    const int rid = t >> 4;            // rows rowBase+4*rid .. +3
    const int rowBase = blockIdx.x * 64;

    const float* xp[4];
    int r[4];
#pragma unroll
    for (int i = 0; i < 4; ++i) {
        r[i] = rowBase + 4 * rid + i;
        xp[i] = X + (size_t)min(r[i], N - 1) * K;
    }

    float acc[4][4] = {};
#pragma unroll 2
    for (int kq = 0; kq < K / 4; ++kq) {
        const int k = kq * 4;
        float4 xv[4], wv[4];
#pragma unroll
        for (int i = 0; i < 4; ++i) xv[i] = *(const float4*)(xp[i] + k);
#pragma unroll
        for (int tt = 0; tt < 4; ++tt) wv[tt] = *(const float4*)&Ws[k + tt][4 * cid];
#pragma unroll
        for (int i = 0; i < 4; ++i) {
            const float* xf = (const float*)&xv[i];
#pragma unroll
            for (int tt = 0; tt < 4; ++tt) {
                const float a = xf[tt];
                const float* wf = (const float*)&wv[tt];
                acc[i][0] += a * wf[0];
                acc[i][1] += a * wf[1];
                acc[i][2] += a * wf[2];
                acc[i][3] += a * wf[3];
            }
        }
    }

#pragma unroll
    for (int i = 0; i < 4; ++i) {
        if (r[i] < N) {
            float sc = rsqrtf((float)max(cnt_out[r[i]], 1));
            float4 o;
            o.x = acc[i][0] * sc; o.y = acc[i][1] * sc;
            o.z = acc[i][2] * sc; o.w = acc[i][3] * sc;
            *(float4*)&Y[(size_t)r[i] * 64 + 4 * cid] = o;
        }
    }
}

// out[n][f] = (sum_{in-edges} Y[src][f]) * rsqrt(max(cnt_in[n],1)) + bias[f]
// One wave per node (lane = feature), 4 nodes / 256-thread block. No atomics.
template <bool RELU>
__global__ __launch_bounds__(256)
void aggregate_kernel(const float* __restrict__ Y,
                      const int* __restrict__ row_ptr,
                      const int* __restrict__ csr_src,
                      const int* __restrict__ cnt_in,
                      const float* __restrict__ bias,
                      float* __restrict__ out, int N) {
    const int f = threadIdx.x & 63;
    const int n = blockIdx.x * 4 + (threadIdx.x >> 6);
    if (n >= N) return;

    const int start = row_ptr[n];
    const int end   = row_ptr[n + 1];

    float acc = 0.f;
    int e = start;
    for (; e + 4 <= end; e += 4) {
        int s0 = csr_src[e];
        int s1 = csr_src[e + 1];
        int s2 = csr_src[e + 2];
        int s3 = csr_src[e + 3];
        float v0 = Y[(size_t)s0 * 64 + f];
        float v1 = Y[(size_t)s1 * 64 + f];
        float v2 = Y[(size_t)s2 * 64 + f];
        float v3 = Y[(size_t)s3 * 64 + f];
        acc += v0 + v1 + v2 + v3;
    }
    for (; e < end; ++e) acc += Y[(size_t)csr_src[e] * 64 + f];

    float sc = rsqrtf((float)max(cnt_in[n], 1));
    float r = acc * sc + bias[f];
    if (RELU) r = fmaxf(r, 0.f);
    out[(size_t)n * 64 + f] = r;
}

extern "C" void kernel_launch(void* const* d_in, const int* in_sizes, int n_in,
                              void* d_out, int out_size, void* d_ws, size_t ws_size,
                              hipStream_t stream) {
    const float* x   = (const float*)d_in[0];
    const int*   src = (const int*)d_in[1];
    const int*   dst = (const int*)d_in[2];
    const float* W1  = (const float*)d_in[3];
    const float* b1  = (const float*)d_in[4];
    const float* W2  = (const float*)d_in[5];
    const float* b2  = (const float*)d_in[6];
    float* out = (float*)d_out;

    const int N = in_sizes[0] / 128;   // 100000
    const int E = in_sizes[1];         // 1600000

    const int SCAN_B = 512;
    const int nb = (N + SCAN_B - 1) / SCAN_B;   // 196 blocks

    // Workspace layout (~33 MB). d_out doubles as the hidden-layer buffer.
    char* ws = (char*)d_ws;
    size_t off = 0;
    float* A        = (float*)(ws + off); off = align256(off + (size_t)N * 64 * sizeof(float));
    int*   csr_src  = (int*)(ws + off);   off = align256(off + (size_t)E * sizeof(int));
    int*   cnt_out  = (int*)(ws + off);   off += (size_t)N * sizeof(int);      // contiguous with
    int*   cnt_in   = (int*)(ws + off);   off = align256(off + (size_t)N * sizeof(int)); // cnt_out
    int*   row_ptr  = (int*)(ws + off);   off = align256(off + (size_t)(N + 1) * sizeof(int));
    int*   cursor   = (int*)(ws + off);   off = align256(off + (size_t)N * sizeof(int));
    int*   blk_sums = (int*)(ws + off);   off = align256(off + (size_t)nb * sizeof(int));

    hipMemsetAsync(cnt_out, 0, (size_t)2 * N * sizeof(int), stream);  // cnt_out + cnt_in

    count_deg_kernel<<<2048, 256, 0, stream>>>(src, dst, cnt_out, cnt_in, E);
    scan_local_kernel<<<nb, SCAN_B, 0, stream>>>(cnt_in, row_ptr, blk_sums, N);
    scan_sums_kernel<<<1, 1024, 0, stream>>>(blk_sums, nb);
    scan_add_kernel<<<nb, SCAN_B, 0, stream>>>(row_ptr, cursor, blk_sums, N, E);
    fill_csr_kernel<<<2048, 256, 0, stream>>>(src, dst, cursor, csr_src, E);

    const int gemm_blocks = (N + 63) / 64;   // 64 rows per block
    const int agg_blocks  = (N + 3) / 4;     // 4 nodes per block

    // Layer 1: Y1 = (X @ W1) * rs_out -> A ; agg -> d_out (hidden, relu)
    gemm_scale_kernel<128><<<gemm_blocks, 256, 0, stream>>>(x, W1, cnt_out, A, N);
    aggregate_kernel<true><<<agg_blocks, 256, 0, stream>>>(A, row_ptr, csr_src, cnt_in, b1, out, N);

    // Layer 2: Y2 = (H @ W2) * rs_out -> A ; agg -> d_out (final)
    gemm_scale_kernel<64><<<gemm_blocks, 256, 0, stream>>>(out, W2, cnt_out, A, N);
    aggregate_kernel<false><<<agg_blocks, 256, 0, stream>>>(A, row_ptr, csr_src, cnt_in, b2, out, N);
}

// Round 4
// 469.040 us; speedup vs baseline: 1.9476x; 1.1834x over previous
//
#include <hip/hip_runtime.h>

// GCN 2-layer: out = D_in^-1/2 A D_out^-1/2 (relu(D_in^-1/2 A D_out^-1/2 X W1 + b1)) W2 + b2
// Strategy: project-then-aggregate (matmul commutes with segment_sum),
// CSR-by-dst built per call (no fp32 atomics in aggregation).
// R1: 3-phase parallel scan (scan was 231 us on one CU).
// R2: register-tiled GEMM — 4x4 outputs/thread, W staged once per block.
// R3: atomic-free CSR fill — count pass records each edge's rank within its
//     dst bucket (atomicAdd return value); fill = pure gather/scatter.
//     (fill_csr was 125 us, atomic-pipe-bound: 32 B HBM-side traffic/atomic.)

static inline size_t align256(size_t x) { return (x + 255) & ~(size_t)255; }

__global__ void count_rank_kernel(const int* __restrict__ src,
                                  const int* __restrict__ dst,
                                  int* __restrict__ cnt_out,
                                  int* __restrict__ cnt_in,
                                  int* __restrict__ rank, int E) {
    int stride = gridDim.x * blockDim.x;
    for (int i = blockIdx.x * blockDim.x + threadIdx.x; i < E; i += stride) {
        rank[i] = atomicAdd(&cnt_in[dst[i]], 1);   // rank within dst bucket
        atomicAdd(&cnt_out[src[i]], 1);
    }
}

// ---- 3-phase parallel exclusive scan of cnt_in -> row_ptr ----
__global__ __launch_bounds__(512)
void scan_local_kernel(const int* __restrict__ cnt_in,
                       int* __restrict__ row_ptr,
                       int* __restrict__ block_sums, int N) {
    __shared__ int tmp[512];
    const int t = threadIdx.x;
    const int gid = blockIdx.x * 512 + t;
    int v = (gid < N) ? cnt_in[gid] : 0;
    tmp[t] = v;
    __syncthreads();
    for (int off = 1; off < 512; off <<= 1) {
        int u = (t >= off) ? tmp[t - off] : 0;
        __syncthreads();
        tmp[t] += u;
        __syncthreads();
    }
    if (gid < N) row_ptr[gid] = tmp[t] - v;      // exclusive
    if (t == 511) block_sums[blockIdx.x] = tmp[511];
}

__global__ __launch_bounds__(1024)
void scan_sums_kernel(int* __restrict__ block_sums, int nb) {
    __shared__ int tmp[1024];
    const int t = threadIdx.x;
    int v = (t < nb) ? block_sums[t] : 0;
    tmp[t] = v;
    __syncthreads();
    for (int off = 1; off < 1024; off <<= 1) {
        int u = (t >= off) ? tmp[t - off] : 0;
        __syncthreads();
        tmp[t] += u;
        __syncthreads();
    }
    if (t < nb) block_sums[t] = tmp[t] - v;      // exclusive
}

__global__ __launch_bounds__(512)
void scan_add_kernel(int* __restrict__ row_ptr,
                     const int* __restrict__ block_sums, int N, int E) {
    const int gid = blockIdx.x * 512 + threadIdx.x;
    if (gid < N) row_ptr[gid] += block_sums[blockIdx.x];
    if (gid == 0) row_ptr[N] = E;
}

// Atomic-free CSR fill using precomputed ranks.
__global__ void fill_csr_kernel(const int* __restrict__ src,
                                const int* __restrict__ dst,
                                const int* __restrict__ rank,
                                const int* __restrict__ row_ptr,
                                int* __restrict__ csr_src, int E) {
    int stride = gridDim.x * blockDim.x;
    for (int i = blockIdx.x * blockDim.x + threadIdx.x; i < E; i += stride) {
        csr_src[row_ptr[dst[i]] + rank[i]] = src[i];
    }
}

// Y[n][j] = (sum_k X[n][k] * W[k][j]) * rsqrt(max(cnt_out[n],1))
// Block: 256 threads = 64 rows x 64 cols; thread computes 4 rows x 4 cols.
template <int K>
__global__ __launch_bounds__(256)
void gemm_scale_kernel(const float* __restrict__ X, const float* __restrict__ W,
                       const int* __restrict__ cnt_out,
                       float* __restrict__ Y, int N) {
    __shared__ float Ws[K][64];
    const int t = threadIdx.x;
    for (int i = t; i < K * 64; i += 256) Ws[i >> 6][i & 63] = W[i];
    __syncthreads();

    const int cid = t & 15;            // cols 4*cid .. 4*cid+3
    const int rid = t >> 4;            // rows rowBase+4*rid .. +3
    const int rowBase = blockIdx.x * 64;

    const float* xp[4];
    int r[4];
#pragma unroll
    for (int i = 0; i < 4; ++i) {
        r[i] = rowBase + 4 * rid + i;
        xp[i] = X + (size_t)min(r[i], N - 1) * K;
    }

    float acc[4][4] = {};
#pragma unroll 2
    for (int kq = 0; kq < K / 4; ++kq) {
        const int k = kq * 4;
        float4 xv[4], wv[4];
#pragma unroll
        for (int i = 0; i < 4; ++i) xv[i] = *(const float4*)(xp[i] + k);
#pragma unroll
        for (int tt = 0; tt < 4; ++tt) wv[tt] = *(const float4*)&Ws[k + tt][4 * cid];
#pragma unroll
        for (int i = 0; i < 4; ++i) {
            const float* xf = (const float*)&xv[i];
#pragma unroll
            for (int tt = 0; tt < 4; ++tt) {
                const float a = xf[tt];
                const float* wf = (const float*)&wv[tt];
                acc[i][0] += a * wf[0];
                acc[i][1] += a * wf[1];
                acc[i][2] += a * wf[2];
                acc[i][3] += a * wf[3];
            }
        }
    }

#pragma unroll
    for (int i = 0; i < 4; ++i) {
        if (r[i] < N) {
            float sc = rsqrtf((float)max(cnt_out[r[i]], 1));
            float4 o;
            o.x = acc[i][0] * sc; o.y = acc[i][1] * sc;
            o.z = acc[i][2] * sc; o.w = acc[i][3] * sc;
            *(float4*)&Y[(size_t)r[i] * 64 + 4 * cid] = o;
        }
    }
}

// out[n][f] = (sum_{in-edges} Y[src][f]) * rsqrt(max(cnt_in[n],1)) + bias[f]
// One wave per node (lane = feature), 4 nodes / 256-thread block. No atomics.
template <bool RELU>
__global__ __launch_bounds__(256)
void aggregate_kernel(const float* __restrict__ Y,
                      const int* __restrict__ row_ptr,
                      const int* __restrict__ csr_src,
                      const int* __restrict__ cnt_in,
                      const float* __restrict__ bias,
                      float* __restrict__ out, int N) {
    const int f = threadIdx.x & 63;
    const int n = blockIdx.x * 4 + (threadIdx.x >> 6);
    if (n >= N) return;

    const int start = row_ptr[n];
    const int end   = row_ptr[n + 1];

    float acc = 0.f;
    int e = start;
    for (; e + 4 <= end; e += 4) {
        int s0 = csr_src[e];
        int s1 = csr_src[e + 1];
        int s2 = csr_src[e + 2];
        int s3 = csr_src[e + 3];
        float v0 = Y[(size_t)s0 * 64 + f];
        float v1 = Y[(size_t)s1 * 64 + f];
        float v2 = Y[(size_t)s2 * 64 + f];
        float v3 = Y[(size_t)s3 * 64 + f];
        acc += v0 + v1 + v2 + v3;
    }
    for (; e < end; ++e) acc += Y[(size_t)csr_src[e] * 64 + f];

    float sc = rsqrtf((float)max(cnt_in[n], 1));
    float r = acc * sc + bias[f];
    if (RELU) r = fmaxf(r, 0.f);
    out[(size_t)n * 64 + f] = r;
}

extern "C" void kernel_launch(void* const* d_in, const int* in_sizes, int n_in,
                              void* d_out, int out_size, void* d_ws, size_t ws_size,
                              hipStream_t stream) {
    const float* x   = (const float*)d_in[0];
    const int*   src = (const int*)d_in[1];
    const int*   dst = (const int*)d_in[2];
    const float* W1  = (const float*)d_in[3];
    const float* b1  = (const float*)d_in[4];
    const float* W2  = (const float*)d_in[5];
    const float* b2  = (const float*)d_in[6];
    float* out = (float*)d_out;

    const int N = in_sizes[0] / 128;   // 100000
    const int E = in_sizes[1];         // 1600000

    const int SCAN_B = 512;
    const int nb = (N + SCAN_B - 1) / SCAN_B;   // 196 blocks

    // Workspace layout (~40 MB). d_out doubles as the hidden-layer buffer.
    char* ws = (char*)d_ws;
    size_t off = 0;
    float* A        = (float*)(ws + off); off = align256(off + (size_t)N * 64 * sizeof(float));
    int*   csr_src  = (int*)(ws + off);   off = align256(off + (size_t)E * sizeof(int));
    int*   rank     = (int*)(ws + off);   off = align256(off + (size_t)E * sizeof(int));
    int*   cnt_out  = (int*)(ws + off);   off += (size_t)N * sizeof(int);      // contiguous with
    int*   cnt_in   = (int*)(ws + off);   off = align256(off + (size_t)N * sizeof(int)); // cnt_out
    int*   row_ptr  = (int*)(ws + off);   off = align256(off + (size_t)(N + 1) * sizeof(int));
    int*   blk_sums = (int*)(ws + off);   off = align256(off + (size_t)nb * sizeof(int));

    hipMemsetAsync(cnt_out, 0, (size_t)2 * N * sizeof(int), stream);  // cnt_out + cnt_in

    count_rank_kernel<<<2048, 256, 0, stream>>>(src, dst, cnt_out, cnt_in, rank, E);
    scan_local_kernel<<<nb, SCAN_B, 0, stream>>>(cnt_in, row_ptr, blk_sums, N);
    scan_sums_kernel<<<1, 1024, 0, stream>>>(blk_sums, nb);
    scan_add_kernel<<<nb, SCAN_B, 0, stream>>>(row_ptr, blk_sums, N, E);
    fill_csr_kernel<<<2048, 256, 0, stream>>>(src, dst, rank, row_ptr, csr_src, E);

    const int gemm_blocks = (N + 63) / 64;   // 64 rows per block
    const int agg_blocks  = (N + 3) / 4;     // 4 nodes per block

    // Layer 1: Y1 = (X @ W1) * rs_out -> A ; agg -> d_out (hidden, relu)
    gemm_scale_kernel<128><<<gemm_blocks, 256, 0, stream>>>(x, W1, cnt_out, A, N);
    aggregate_kernel<true><<<agg_blocks, 256, 0, stream>>>(A, row_ptr, csr_src, cnt_in, b1, out, N);

    // Layer 2: Y2 = (H @ W2) * rs_out -> A ; agg -> d_out (final)
    gemm_scale_kernel<64><<<gemm_blocks, 256, 0, stream>>>(out, W2, cnt_out, A, N);
    aggregate_kernel<false><<<agg_blocks, 256, 0, stream>>>(A, row_ptr, csr_src, cnt_in, b2, out, N);
}

// Round 5
// 440.447 us; speedup vs baseline: 2.0740x; 1.0649x over previous
//
#include <hip/hip_runtime.h>
#include <hip/hip_fp16.h>

// GCN 2-layer: out = D_in^-1/2 A D_out^-1/2 (relu(D_in^-1/2 A D_out^-1/2 X W1 + b1)) W2 + b2
// Strategy: project-then-aggregate (matmul commutes with segment_sum),
// CSR-by-dst built per call (no fp32 atomics in aggregation).
// R1: 3-phase parallel scan (scan was 231 us on one CU).
// R2: register-tiled GEMM — 4x4 outputs/thread, W staged once per block.
// R3: atomic-free CSR fill via atomicAdd-returned ranks.
// R4: (a) cnt_out via LDS-binned histogram (device atomics 3.2M -> 1.6M;
//         atomic pipe measured ~26 G ops/s is the bound);
//     (b) Y stored fp16 — halves the 410 MB aggregate gather traffic.

static inline size_t align256(size_t x) { return (x + 255) & ~(size_t)255; }

// Only the cnt_in/rank atomic remains device-scope (needed for CSR ranks).
__global__ void rank_kernel(const int* __restrict__ dst,
                            int* __restrict__ cnt_in,
                            int* __restrict__ rank, int E) {
    int stride = gridDim.x * blockDim.x;
    for (int i = blockIdx.x * blockDim.x + threadIdx.x; i < E; i += stride) {
        rank[i] = atomicAdd(&cnt_in[dst[i]], 1);   // rank within dst bucket
    }
}

// ---- cnt_out histogram: LDS-binned partials, no device-scope atomics ----
#define HIST_BIN 8192
#define HIST_SLICES 64
__global__ __launch_bounds__(256)
void hist_partial_kernel(const int* __restrict__ src,
                         int* __restrict__ partial,   // [HIST_SLICES][N]
                         int N, int E, int slice_len) {
    __shared__ int h[HIST_BIN];
    const int s = blockIdx.x;            // edge slice
    const int lo = blockIdx.y * HIST_BIN; // node-bin base
    for (int i = threadIdx.x; i < HIST_BIN; i += 256) h[i] = 0;
    __syncthreads();
    const int beg = s * slice_len;
    const int end = min(beg + slice_len, E);
    for (int i = beg + threadIdx.x; i < end; i += 256) {
        int v = src[i] - lo;
        if ((unsigned)v < (unsigned)HIST_BIN) atomicAdd(&h[v], 1);  // LDS atomic
    }
    __syncthreads();
    const int hi = min(lo + HIST_BIN, N);
    int* p = partial + (size_t)s * N;
    for (int v = lo + threadIdx.x; v < hi; v += 256) p[v] = h[v - lo];
}

__global__ void hist_reduce_kernel(const int* __restrict__ partial,
                                   int* __restrict__ cnt_out, int N) {
    const int v = blockIdx.x * 256 + threadIdx.x;
    if (v >= N) return;
    int sum = 0;
#pragma unroll 4
    for (int s = 0; s < HIST_SLICES; ++s) sum += partial[(size_t)s * N + v];
    cnt_out[v] = sum;
}

// ---- 3-phase parallel exclusive scan of cnt_in -> row_ptr ----
__global__ __launch_bounds__(512)
void scan_local_kernel(const int* __restrict__ cnt_in,
                       int* __restrict__ row_ptr,
                       int* __restrict__ block_sums, int N) {
    __shared__ int tmp[512];
    const int t = threadIdx.x;
    const int gid = blockIdx.x * 512 + t;
    int v = (gid < N) ? cnt_in[gid] : 0;
    tmp[t] = v;
    __syncthreads();
    for (int off = 1; off < 512; off <<= 1) {
        int u = (t >= off) ? tmp[t - off] : 0;
        __syncthreads();
        tmp[t] += u;
        __syncthreads();
    }
    if (gid < N) row_ptr[gid] = tmp[t] - v;      // exclusive
    if (t == 511) block_sums[blockIdx.x] = tmp[511];
}

__global__ __launch_bounds__(1024)
void scan_sums_kernel(int* __restrict__ block_sums, int nb) {
    __shared__ int tmp[1024];
    const int t = threadIdx.x;
    int v = (t < nb) ? block_sums[t] : 0;
    tmp[t] = v;
    __syncthreads();
    for (int off = 1; off < 1024; off <<= 1) {
        int u = (t >= off) ? tmp[t - off] : 0;
        __syncthreads();
        tmp[t] += u;
        __syncthreads();
    }
    if (t < nb) block_sums[t] = tmp[t] - v;      // exclusive
}

__global__ __launch_bounds__(512)
void scan_add_kernel(int* __restrict__ row_ptr,
                     const int* __restrict__ block_sums, int N, int E) {
    const int gid = blockIdx.x * 512 + threadIdx.x;
    if (gid < N) row_ptr[gid] += block_sums[blockIdx.x];
    if (gid == 0) row_ptr[N] = E;
}

// Atomic-free CSR fill using precomputed ranks.
__global__ void fill_csr_kernel(const int* __restrict__ src,
                                const int* __restrict__ dst,
                                const int* __restrict__ rank,
                                const int* __restrict__ row_ptr,
                                int* __restrict__ csr_src, int E) {
    int stride = gridDim.x * blockDim.x;
    for (int i = blockIdx.x * blockDim.x + threadIdx.x; i < E; i += stride) {
        csr_src[row_ptr[dst[i]] + rank[i]] = src[i];
    }
}

// Y[n][j] = (sum_k X[n][k] * W[k][j]) * rsqrt(max(cnt_out[n],1)), stored fp16.
// Block: 256 threads = 64 rows x 64 cols; thread computes 4 rows x 4 cols.
template <int K>
__global__ __launch_bounds__(256)
void gemm_scale_kernel(const float* __restrict__ X, const float* __restrict__ W,
                       const int* __restrict__ cnt_out,
                       __half* __restrict__ Y, int N) {
    __shared__ float Ws[K][64];
    const int t = threadIdx.x;
    for (int i = t; i < K * 64; i += 256) Ws[i >> 6][i & 63] = W[i];
    __syncthreads();

    const int cid = t & 15;            // cols 4*cid .. 4*cid+3
    const int rid = t >> 4;            // rows rowBase+4*rid .. +3
    const int rowBase = blockIdx.x * 64;

    const float* xp[4];
    int r[4];
#pragma unroll
    for (int i = 0; i < 4; ++i) {
        r[i] = rowBase + 4 * rid + i;
        xp[i] = X + (size_t)min(r[i], N - 1) * K;
    }

    float acc[4][4] = {};
#pragma unroll 2
    for (int kq = 0; kq < K / 4; ++kq) {
        const int k = kq * 4;
        float4 xv[4], wv[4];
#pragma unroll
        for (int i = 0; i < 4; ++i) xv[i] = *(const float4*)(xp[i] + k);
#pragma unroll
        for (int tt = 0; tt < 4; ++tt) wv[tt] = *(const float4*)&Ws[k + tt][4 * cid];
#pragma unroll
        for (int i = 0; i < 4; ++i) {
            const float* xf = (const float*)&xv[i];
#pragma unroll
            for (int tt = 0; tt < 4; ++tt) {
                const float a = xf[tt];
                const float* wf = (const float*)&wv[tt];
                acc[i][0] += a * wf[0];
                acc[i][1] += a * wf[1];
                acc[i][2] += a * wf[2];
                acc[i][3] += a * wf[3];
            }
        }
    }

#pragma unroll
    for (int i = 0; i < 4; ++i) {
        if (r[i] < N) {
            float sc = rsqrtf((float)max(cnt_out[r[i]], 1));
            __half2* yp = (__half2*)&Y[(size_t)r[i] * 64 + 4 * cid];
            yp[0] = __halves2half2(__float2half_rn(acc[i][0] * sc),
                                   __float2half_rn(acc[i][1] * sc));
            yp[1] = __halves2half2(__float2half_rn(acc[i][2] * sc),
                                   __float2half_rn(acc[i][3] * sc));
        }
    }
}

// out[n][f] = (sum_{in-edges} Y[src][f]) * rsqrt(max(cnt_in[n],1)) + bias[f]
// One wave per node (lane = feature), 4 nodes / 256-thread block. No atomics.
// Y is fp16 (halves gather traffic; working set 12.8 MB -> L2-friendlier).
template <bool RELU>
__global__ __launch_bounds__(256)
void aggregate_kernel(const __half* __restrict__ Y,
                      const int* __restrict__ row_ptr,
                      const int* __restrict__ csr_src,
                      const int* __restrict__ cnt_in,
                      const float* __restrict__ bias,
                      float* __restrict__ out, int N) {
    const int f = threadIdx.x & 63;
    const int n = blockIdx.x * 4 + (threadIdx.x >> 6);
    if (n >= N) return;

    const int start = row_ptr[n];
    const int end   = row_ptr[n + 1];

    float acc = 0.f;
    int e = start;
    for (; e + 4 <= end; e += 4) {
        int s0 = csr_src[e];
        int s1 = csr_src[e + 1];
        int s2 = csr_src[e + 2];
        int s3 = csr_src[e + 3];
        float v0 = __half2float(Y[(size_t)s0 * 64 + f]);
        float v1 = __half2float(Y[(size_t)s1 * 64 + f]);
        float v2 = __half2float(Y[(size_t)s2 * 64 + f]);
        float v3 = __half2float(Y[(size_t)s3 * 64 + f]);
        acc += v0 + v1 + v2 + v3;
    }
    for (; e < end; ++e) acc += __half2float(Y[(size_t)csr_src[e] * 64 + f]);

    float sc = rsqrtf((float)max(cnt_in[n], 1));
    float r = acc * sc + bias[f];
    if (RELU) r = fmaxf(r, 0.f);
    out[(size_t)n * 64 + f] = r;
}

extern "C" void kernel_launch(void* const* d_in, const int* in_sizes, int n_in,
                              void* d_out, int out_size, void* d_ws, size_t ws_size,
                              hipStream_t stream) {
    const float* x   = (const float*)d_in[0];
    const int*   src = (const int*)d_in[1];
    const int*   dst = (const int*)d_in[2];
    const float* W1  = (const float*)d_in[3];
    const float* b1  = (const float*)d_in[4];
    const float* W2  = (const float*)d_in[5];
    const float* b2  = (const float*)d_in[6];
    float* out = (float*)d_out;

    const int N = in_sizes[0] / 128;   // 100000
    const int E = in_sizes[1];         // 1600000

    const int SCAN_B = 512;
    const int nb = (N + SCAN_B - 1) / SCAN_B;   // 196 blocks

    // Workspace (~40 MB). Region "A" (64*N ints = 25.6 MB) is time-shared:
    //   phase 1: hist partials [64][N] ints; phase 2+: Y fp16 (N*64*2 B).
    // d_out doubles as the hidden-layer (H) buffer.
    char* ws = (char*)d_ws;
    size_t off = 0;
    int*    Aregion  = (int*)(ws + off);  off = align256(off + (size_t)HIST_SLICES * N * sizeof(int));
    int*    csr_src  = (int*)(ws + off);  off = align256(off + (size_t)E * sizeof(int));
    int*    rank     = (int*)(ws + off);  off = align256(off + (size_t)E * sizeof(int));
    int*    cnt_out  = (int*)(ws + off);  off += (size_t)N * sizeof(int);
    int*    cnt_in   = (int*)(ws + off);  off = align256(off + (size_t)N * sizeof(int));
    int*    row_ptr  = (int*)(ws + off);  off = align256(off + (size_t)(N + 1) * sizeof(int));
    int*    blk_sums = (int*)(ws + off);  off = align256(off + (size_t)nb * sizeof(int));

    int*    partial = Aregion;            // [HIST_SLICES][N]
    __half* Y       = (__half*)Aregion;   // fp16 projected features

    hipMemsetAsync(cnt_in, 0, (size_t)N * sizeof(int), stream);

    // cnt_out histogram (no device atomics)
    const int slice_len = (E + HIST_SLICES - 1) / HIST_SLICES;
    const int nbins = (N + HIST_BIN - 1) / HIST_BIN;
    hist_partial_kernel<<<dim3(HIST_SLICES, nbins), 256, 0, stream>>>(src, partial, N, E, slice_len);
    hist_reduce_kernel<<<(N + 255) / 256, 256, 0, stream>>>(partial, cnt_out, N);

    // cnt_in + ranks (1.6M device atomics), scan, CSR fill
    rank_kernel<<<2048, 256, 0, stream>>>(dst, cnt_in, rank, E);
    scan_local_kernel<<<nb, SCAN_B, 0, stream>>>(cnt_in, row_ptr, blk_sums, N);
    scan_sums_kernel<<<1, 1024, 0, stream>>>(blk_sums, nb);
    scan_add_kernel<<<nb, SCAN_B, 0, stream>>>(row_ptr, blk_sums, N, E);
    fill_csr_kernel<<<2048, 256, 0, stream>>>(src, dst, rank, row_ptr, csr_src, E);

    const int gemm_blocks = (N + 63) / 64;   // 64 rows per block
    const int agg_blocks  = (N + 3) / 4;     // 4 nodes per block

    // Layer 1: Y = fp16[(X @ W1) * rs_out] ; agg -> d_out (hidden, relu)
    gemm_scale_kernel<128><<<gemm_blocks, 256, 0, stream>>>(x, W1, cnt_out, Y, N);
    aggregate_kernel<true><<<agg_blocks, 256, 0, stream>>>(Y, row_ptr, csr_src, cnt_in, b1, out, N);

    // Layer 2: Y = fp16[(H @ W2) * rs_out] ; agg -> d_out (final)
    gemm_scale_kernel<64><<<gemm_blocks, 256, 0, stream>>>(out, W2, cnt_out, Y, N);
    aggregate_kernel<false><<<agg_blocks, 256, 0, stream>>>(Y, row_ptr, csr_src, cnt_in, b2, out, N);
}